// Round 7
// baseline (10277.969 us; speedup 1.0000x reference)
//
#include <hip/hip_runtime.h>
#include <hip/hip_bf16.h>

typedef unsigned short u16;
typedef unsigned int   u32;
typedef unsigned long long u64;
typedef short short8 __attribute__((ext_vector_type(8)));
typedef float f32x4  __attribute__((ext_vector_type(4)));
typedef u16   u16x4  __attribute__((ext_vector_type(4)));

#define T_STEPS 512
#define BATCH   64
#define HD      1024
#define NBLK    128    // 32 gate-cols per block, 1 block/CU
#define NTHR    512    // 8 waves: 4 x-waves + 4 h-waves -> 2 waves/SIMD
#define NCOL    32
#define WKS     2056   // K-stride in LDS elems (pad -> conflict-free b128 reads)
#define HBUF_E  (BATCH * HD)   // elems per h ring buffer (128 KB)
#define GDEPTH  3              // g_x LDS ring depth (x-waves run <=2 steps ahead)
#define GSTR    33
#define GSLOT_F (BATCH * GSTR)         // floats per g slot
#define GSLOT_B (GSLOT_F * 4)          // 8448 B

// LDS layout (bytes)
#define W_BYTES 131584                       // NCOL * WKS * 2
#define G_OFF   W_BYTES
#define B_OFF   (G_OFF + GDEPTH * GSLOT_B)   // 156928
#define L_OFF   (B_OFF + 128)                // 157056: lf[0..3]=xdone, [4..7]=hmerged,
#define SMEM_BYTES (L_OFF + 64)              // [8..11]=gdone, [12]=bf16flag. 157120 < 160K

__device__ __forceinline__ float sigm(float x) { return 1.f / (1.f + __expf(-x)); }
__device__ __forceinline__ float tanh_(float x) {
    float ax = __builtin_fabsf(x);
    float e  = __expf(-2.f * ax);
    float r  = (1.f - e) / (1.f + e);
    return x < 0.f ? -r : r;
}
__device__ __forceinline__ short bfb(float f) {          // fp32 -> bf16 bits (RNE)
    __hip_bfloat16 h = __float2bfloat16(f);
    return *(short*)&h;
}

// Intra-CU LDS flags (workgroup scope -> ds ops, ~30 cyc)
__device__ __forceinline__ int  lds_ld(int* p) {
    return __hip_atomic_load(p, __ATOMIC_RELAXED, __HIP_MEMORY_SCOPE_WORKGROUP);
}
__device__ __forceinline__ void lds_st(int* p, int v) {
    __hip_atomic_store(p, v, __ATOMIC_RELAXED, __HIP_MEMORY_SCOPE_WORKGROUP);
}
__device__ __forceinline__ void lds_spin_ge(int* p, int target) {
    while (lds_ld(p) < target) __builtin_amdgcn_s_sleep(1);
    asm volatile("" ::: "memory");
}

// Dtype probe: packed-bf16 x -> low-u16 exponent in [100,140] ~always;
// fp32 x -> mantissa junk, ~uniform. 18-sigma separation at threshold 128.
__device__ int detect_bf16(const u32* __restrict__ x) {
    int c = 0;
#pragma unroll 8
    for (int i = 0; i < 256; ++i) {
        u32 e = (x[i] >> 7) & 0xFF;
        c += (e >= 100 && e <= 140) ? 1 : 0;
    }
    return c >= 128;
}

extern "C" __global__ void __launch_bounds__(256)
cvt_x_kernel(const void* __restrict__ x, u16* __restrict__ xb, int n4)
{
    __shared__ int flg;
    if (threadIdx.x == 0) flg = detect_bf16((const u32*)x);
    __syncthreads();
    if (flg) return;
    const float4* xf = (const float4*)x;
    u16x4* xo = (u16x4*)xb;
    for (int i = blockIdx.x * blockDim.x + threadIdx.x; i < n4;
         i += gridDim.x * blockDim.x) {
        float4 v = xf[i];
        u16x4 o;
        o[0] = (u16)bfb(v.x); o[1] = (u16)bfb(v.y);
        o[2] = (u16)bfb(v.z); o[3] = (u16)bfb(v.w);
        xo[i] = o;
    }
}

union Frag16 { u64 q[2]; short8 s8[1]; };

// Load one K-chunk (4 MFMA-iters) of h A-frags for TWO row-tiles.
__device__ __forceinline__ void load_chunk2(const u16* hp0, const u16* hp1, int c,
                                            Frag16* b0, Frag16* b1, int ring_on) {
    if (ring_on) {
#pragma unroll
        for (int it = 0; it < 4; ++it) {
            b0[it].s8[0] = *(const short8*)(hp0 + c * 128 + it * 32);
            b1[it].s8[0] = *(const short8*)(hp1 + c * 128 + it * 32);
        }
    } else {
#pragma unroll
        for (int it = 0; it < 4; ++it) {
            const u16* p0 = hp0 + c * 128 + it * 32;
            const u16* p1 = hp1 + c * 128 + it * 32;
            b0[it].q[0] = __hip_atomic_load((const u64*)p0,     __ATOMIC_RELAXED, __HIP_MEMORY_SCOPE_AGENT);
            b0[it].q[1] = __hip_atomic_load((const u64*)(p0+4), __ATOMIC_RELAXED, __HIP_MEMORY_SCOPE_AGENT);
            b1[it].q[0] = __hip_atomic_load((const u64*)p1,     __ATOMIC_RELAXED, __HIP_MEMORY_SCOPE_AGENT);
            b1[it].q[1] = __hip_atomic_load((const u64*)(p1+4), __ATOMIC_RELAXED, __HIP_MEMORY_SCOPE_AGENT);
        }
    }
}

// Spin until both h-wave flags (row-class mh) of all 16 producer blocks of chunk c hit t.
__device__ __forceinline__ void poll_chunk(const int* flags, int c, int mh,
                                           int t, int lane) {
    const int idx = 64 * c + 4 * (lane & 15) + 2 * mh;
    while (true) {
        int fa = __hip_atomic_load(&flags[idx],     __ATOMIC_RELAXED, __HIP_MEMORY_SCOPE_AGENT);
        int fb = __hip_atomic_load(&flags[idx + 1], __ATOMIC_RELAXED, __HIP_MEMORY_SCOPE_AGENT);
        if (__all(fa >= t && fb >= t)) break;
        __builtin_amdgcn_s_sleep(1);
    }
    asm volatile("" ::: "memory");
}

extern "C" __global__ void __launch_bounds__(NTHR, 2)
lstm_persistent(const void* __restrict__ x,
                const void* __restrict__ Wxf, const void* __restrict__ Wxi,
                const void* __restrict__ Wxg, const void* __restrict__ Wxo,
                const void* __restrict__ Whf, const void* __restrict__ Whi,
                const void* __restrict__ Whg, const void* __restrict__ Who,
                const void* __restrict__ bxf, const void* __restrict__ bxi,
                const void* __restrict__ bxg, const void* __restrict__ bxo,
                const void* __restrict__ bhf, const void* __restrict__ bhi,
                const void* __restrict__ bhg, const void* __restrict__ bho,
                u16* __restrict__ hring, int ring_on,
                u16* __restrict__ xb, int* __restrict__ flags,
                void* __restrict__ outv)
{
    // One-time agent acquire: invalidate L1/L2 of poison/prior-replay ring lines.
    __builtin_amdgcn_fence(__ATOMIC_ACQUIRE, "agent");

    extern __shared__ char smem[];
    u16*   w_lds = (u16*)smem;
    float* g_lds = (float*)(smem + G_OFF);
    float* b_lds = (float*)(smem + B_OFF);
    int*   lf    = (int*)(smem + L_OFF);

    const int tid  = threadIdx.x;
    const int blk  = blockIdx.x;
    const int wv   = tid >> 6;
    const int lane = tid & 63;

    if (tid < 12) lds_st(&lf[tid], 0);
    if (tid == 0) lds_st(&lf[12], detect_bf16((const u32*)x));
    __syncthreads();
    const int bf16mode = lds_ld(&lf[12]);

    // ---- Stage weight slice once (bf16): cols [8*blk, 8*blk+8) of gates f,i,g,o.
    //      LDS: [gate-col][K], K = 1024 x-side then 1024 h-side, k-contiguous.
    {
        const int gate = wv & 3;      // wave-uniform
        const int kh   = wv >> 2;
        const int kb   = lane;
        const void* WX[4] = {Wxf, Wxi, Wxg, Wxo};
        const void* WH[4] = {Whf, Whi, Whg, Who};
        for (int it = 0; it < 8; ++it) {
            int k = kh * 512 + it * 64 + kb;
            u16 vx[8], vh[8];
            if (bf16mode) {
                short8 a = *(const short8*)((const u16*)WX[gate] + (size_t)k * HD + blk * 8);
                short8 b = *(const short8*)((const u16*)WH[gate] + (size_t)k * HD + blk * 8);
#pragma unroll
                for (int ci = 0; ci < 8; ++ci) { vx[ci] = (u16)a[ci]; vh[ci] = (u16)b[ci]; }
            } else {
                const float* px = (const float*)WX[gate] + (size_t)k * HD + blk * 8;
                const float* ph = (const float*)WH[gate] + (size_t)k * HD + blk * 8;
                float4 a0 = *(const float4*)px, a1 = *(const float4*)(px + 4);
                float4 b0 = *(const float4*)ph, b1 = *(const float4*)(ph + 4);
                vx[0]=(u16)bfb(a0.x); vx[1]=(u16)bfb(a0.y); vx[2]=(u16)bfb(a0.z); vx[3]=(u16)bfb(a0.w);
                vx[4]=(u16)bfb(a1.x); vx[5]=(u16)bfb(a1.y); vx[6]=(u16)bfb(a1.z); vx[7]=(u16)bfb(a1.w);
                vh[0]=(u16)bfb(b0.x); vh[1]=(u16)bfb(b0.y); vh[2]=(u16)bfb(b0.z); vh[3]=(u16)bfb(b0.w);
                vh[4]=(u16)bfb(b1.x); vh[5]=(u16)bfb(b1.y); vh[6]=(u16)bfb(b1.z); vh[7]=(u16)bfb(b1.w);
            }
#pragma unroll
            for (int ci = 0; ci < 8; ++ci) {
                w_lds[(gate * 8 + ci) * WKS + k]        = vx[ci];
                w_lds[(gate * 8 + ci) * WKS + 1024 + k] = vh[ci];
            }
        }
    }
    if (tid < NCOL) {
        const void* BX[4] = {bxf, bxi, bxg, bxo};
        const void* BH[4] = {bhf, bhi, bhg, bho};
        int gate = tid >> 3, hc = blk * 8 + (tid & 7);
        float v;
        if (bf16mode)
            v = __bfloat162float(((const __hip_bfloat16*)BX[gate])[hc]) +
                __bfloat162float(((const __hip_bfloat16*)BH[gate])[hc]);
        else
            v = ((const float*)BX[gate])[hc] + ((const float*)BH[gate])[hc];
        b_lds[tid] = v;
    }
    __syncthreads();   // last block-wide sync: w_lds/b_lds read-only, lf zeroed

    // Wave roles: wv 0-3 = x-waves, 4-7 = h-waves; pair pw = (mh,nh).
    const int pw = wv & 3;
    const int mh = pw >> 1;          // 32-row half of the batch
    const int nh = pw & 1;           // 16-col half of the 32 gate-cols
    const int c16  = lane & 15;
    const int quad = lane >> 4;
    const int arow0 = mh * 32 + c16;           // A rows: tile0, tile1 = +16
    const u16* wbase = w_lds + (nh * 16 + c16) * WKS + quad * 8;

    const int use16 = bf16mode || (xb != nullptr);

    if (wv < 4) {
        // ================= x-wave: g_x[t] = x_t @ Wx into LDS g-ring =================
        const u16*   x16l0 = nullptr; const u16*   x16l1 = nullptr;
        const float* xf_l0 = nullptr; const float* xf_l1 = nullptr;
        if (use16) {
            const u16* x16 = bf16mode ? (const u16*)x : xb;
            x16l0 = x16 + (size_t)arow0 * T_STEPS * HD + quad * 8;
            x16l1 = x16l0 + (size_t)16 * T_STEPS * HD;
        } else {
            xf_l0 = (const float*)x + (size_t)arow0 * T_STEPS * HD + quad * 8;
            xf_l1 = xf_l0 + (size_t)16 * T_STEPS * HD;
        }
        for (int t = 0; t < T_STEPS; ++t) {
            if (t >= GDEPTH) {       // slot (t%GDEPTH) free once step t-GDEPTH gated
                lds_spin_ge(&lf[8 + 2 * mh],     t - GDEPTH + 1);
                lds_spin_ge(&lf[8 + 2 * mh + 1], t - GDEPTH + 1);
            }
            f32x4 a0 = {0.f,0.f,0.f,0.f}, a1 = {0.f,0.f,0.f,0.f};
            if (use16) {
                const u16* xp0 = x16l0 + (size_t)t * HD;
                const u16* xp1 = x16l1 + (size_t)t * HD;
#pragma unroll 8
                for (int kc = 0; kc < 32; ++kc) {
                    short8 b  = *(const short8*)(wbase + kc * 32);   // B reused 2x
                    short8 f0 = *(const short8*)(xp0 + kc * 32);
                    short8 f1 = *(const short8*)(xp1 + kc * 32);
                    a0 = __builtin_amdgcn_mfma_f32_16x16x32_bf16(f0, b, a0, 0, 0, 0);
                    a1 = __builtin_amdgcn_mfma_f32_16x16x32_bf16(f1, b, a1, 0, 0, 0);
                }
            } else {
                const float* xp0 = xf_l0 + (size_t)t * HD;
                const float* xp1 = xf_l1 + (size_t)t * HD;
#pragma unroll 4
                for (int kc = 0; kc < 32; ++kc) {
                    float4 fa = *(const float4*)(xp0 + kc * 32);
                    float4 fb = *(const float4*)(xp0 + kc * 32 + 4);
                    float4 fc = *(const float4*)(xp1 + kc * 32);
                    float4 fd = *(const float4*)(xp1 + kc * 32 + 4);
                    short8 f0 = {bfb(fa.x), bfb(fa.y), bfb(fa.z), bfb(fa.w),
                                 bfb(fb.x), bfb(fb.y), bfb(fb.z), bfb(fb.w)};
                    short8 f1 = {bfb(fc.x), bfb(fc.y), bfb(fc.z), bfb(fc.w),
                                 bfb(fd.x), bfb(fd.y), bfb(fd.z), bfb(fd.w)};
                    short8 b  = *(const short8*)(wbase + kc * 32);
                    a0 = __builtin_amdgcn_mfma_f32_16x16x32_bf16(f0, b, a0, 0, 0, 0);
                    a1 = __builtin_amdgcn_mfma_f32_16x16x32_bf16(f1, b, a1, 0, 0, 0);
                }
            }
            float* gs = g_lds + (t % GDEPTH) * GSLOT_F;
#pragma unroll
            for (int r = 0; r < 4; ++r) {
                gs[(mh * 32 +      quad * 4 + r) * GSTR + nh * 16 + c16] = a0[r];
                gs[(mh * 32 + 16 + quad * 4 + r) * GSTR + nh * 16 + c16] = a1[r];
            }
            asm volatile("s_waitcnt lgkmcnt(0)" ::: "memory");
            if (lane == 0) lds_st(&lf[pw], t + 1);   // xdone
        }
    } else {
        // ================= h-wave: poll -> h-K -> merge -> gates -> publish ==========
        const int grow = mh * 32 + (lane >> 1);     // gate-phase row
        const int hl0  = nh * 4 + (lane & 1) * 2;   // 2 adjacent local h-cols
        float bias[8];
#pragma unroll
        for (int g = 0; g < 4; ++g) {
            bias[g * 2]     = b_lds[g * 8 + hl0];
            bias[g * 2 + 1] = b_lds[g * 8 + hl0 + 1];
        }
        float creg[2] = {0.f, 0.f};
        const int c0 = blk >> 4;

        for (int t = 0; t < T_STEPS; ++t) {
            f32x4 a0 = {0.f,0.f,0.f,0.f}, a1 = {0.f,0.f,0.f,0.f};

            if (t > 0) {
                const u16* hb  = hring + (size_t)(ring_on ? (t - 1) : (t & 1)) * HBUF_E;
                const u16* hp0 = hb + (size_t)arow0 * HD + quad * 8;
                const u16* hp1 = hp0 + (size_t)16 * HD;

                // one flag sweep -> all 8 chunk-ready bits (4 loads + 2 ballots)
                int fa1 = __hip_atomic_load(&flags[4 * lane + 2 * mh],           __ATOMIC_RELAXED, __HIP_MEMORY_SCOPE_AGENT);
                int fb1 = __hip_atomic_load(&flags[4 * lane + 2 * mh + 1],       __ATOMIC_RELAXED, __HIP_MEMORY_SCOPE_AGENT);
                int fa2 = __hip_atomic_load(&flags[256 + 4 * lane + 2 * mh],     __ATOMIC_RELAXED, __HIP_MEMORY_SCOPE_AGENT);
                int fb2 = __hip_atomic_load(&flags[256 + 4 * lane + 2 * mh + 1], __ATOMIC_RELAXED, __HIP_MEMORY_SCOPE_AGENT);
                u64 m1 = __ballot(fa1 >= t && fb1 >= t);
                u64 m2 = __ballot(fa2 >= t && fb2 >= t);
                asm volatile("" ::: "memory");

                Frag16 A0a[4], A1a[4], A0b[4], A1b[4];
                {
                    u64 m = (c0 < 4) ? (m1 >> (16 * c0)) : (m2 >> (16 * (c0 - 4)));
                    if ((m & 0xFFFFull) != 0xFFFFull) poll_chunk(flags, c0, mh, t, lane);
                }
                load_chunk2(hp0, hp1, c0, A0a, A1a, ring_on);

#pragma unroll
                for (int ci = 0; ci < 8; ++ci) {
                    const int cc = (c0 + ci) & 7;
                    Frag16* c0p = (ci & 1) ? A0b : A0a;
                    Frag16* c1p = (ci & 1) ? A1b : A1a;
                    Frag16* n0p = (ci & 1) ? A0a : A0b;
                    Frag16* n1p = (ci & 1) ? A1a : A1b;
                    if (ci < 7) {
                        const int cn = (c0 + ci + 1) & 7;
                        u64 m = (cn < 4) ? (m1 >> (16 * cn)) : (m2 >> (16 * (cn - 4)));
                        if ((m & 0xFFFFull) != 0xFFFFull) poll_chunk(flags, cn, mh, t, lane);
                        load_chunk2(hp0, hp1, cn, n0p, n1p, ring_on);
                    }
#pragma unroll
                    for (int it = 0; it < 4; ++it) {
                        short8 b = *(const short8*)(wbase + 1024 + cc * 128 + it * 32);
                        a0 = __builtin_amdgcn_mfma_f32_16x16x32_bf16(c0p[it].s8[0], b, a0, 0, 0, 0);
                        a1 = __builtin_amdgcn_mfma_f32_16x16x32_bf16(c1p[it].s8[0], b, a1, 0, 0, 0);
                    }
                }
            }

            // merge with g_x (in place); x-wave guaranteed ahead via xdone
            lds_spin_ge(&lf[pw], t + 1);
            float* gs = g_lds + (t % GDEPTH) * GSLOT_F;
#pragma unroll
            for (int r = 0; r < 4; ++r) {
                int i0 = (mh * 32 +      quad * 4 + r) * GSTR + nh * 16 + c16;
                int i1 = (mh * 32 + 16 + quad * 4 + r) * GSTR + nh * 16 + c16;
                gs[i0] += a0[r];
                gs[i1] += a1[r];
            }
            asm volatile("s_waitcnt lgkmcnt(0)" ::: "memory");
            if (lane == 0) lds_st(&lf[4 + pw], t + 1);          // hmerged (own half)
            lds_spin_ge(&lf[4 + 2 * mh + (1 - nh)], t + 1);     // peer half ready

            // gates: rows mh*32..+32, h-cols hl0, hl0+1 (c-state in regs)
            float hv[2], cv[2];
#pragma unroll
            for (int jj = 0; jj < 2; ++jj) {
                int hl = hl0 + jj;
                float gf = gs[grow * GSTR + hl]      + bias[jj];
                float gi = gs[grow * GSTR + 8 + hl]  + bias[2 + jj];
                float gg = gs[grow * GSTR + 16 + hl] + bias[4 + jj];
                float go = gs[grow * GSTR + 24 + hl] + bias[6 + jj];
                float fg = sigm(gf), ig = sigm(gi), og = sigm(go);
                float gt = tanh_(gg);
                float cnew = fg * creg[jj] + ig * gt;
                creg[jj] = cnew;
                cv[jj] = cnew;
                hv[jj] = tanh_(cnew) * og;
            }
            asm volatile("s_waitcnt lgkmcnt(0)" ::: "memory");
            if (lane == 0) lds_st(&lf[8 + pw], t + 1);          // gdone -> slot freed

            if (t < T_STEPS - 1) {
                u32 pk = (u32)(u16)bfb(hv[0]) | ((u32)(u16)bfb(hv[1]) << 16);
                u16* hn = hring + (size_t)(ring_on ? t : ((t + 1) & 1)) * HBUF_E;
                __hip_atomic_store((u32*)(hn + (size_t)grow * HD + blk * 8 + hl0), pk,
                                   __ATOMIC_RELAXED, __HIP_MEMORY_SCOPE_AGENT);
                asm volatile("s_waitcnt vmcnt(0)" ::: "memory");
                if (lane == 0)
                    __hip_atomic_store(&flags[4 * blk + pw], t + 1, __ATOMIC_RELAXED,
                                       __HIP_MEMORY_SCOPE_AGENT);
            } else {
#pragma unroll
                for (int jj = 0; jj < 2; ++jj) {
                    size_t idx = (size_t)grow * HD + blk * 8 + hl0 + jj;
                    if (bf16mode) {
                        u16* o = (u16*)outv;
                        __hip_bfloat16 hb2 = __float2bfloat16(hv[jj]);
                        __hip_bfloat16 cb2 = __float2bfloat16(cv[jj]);
                        o[idx] = *(u16*)&hb2;
                        o[(size_t)BATCH * HD + idx] = *(u16*)&cb2;
                    } else {
                        float* o = (float*)outv;
                        o[idx] = hv[jj];
                        o[(size_t)BATCH * HD + idx] = cv[jj];
                    }
                }
            }
        }
    }
}

extern "C" void kernel_launch(void* const* d_in, const int* in_sizes, int n_in,
                              void* d_out, int out_size, void* d_ws, size_t ws_size,
                              hipStream_t stream) {
    (void)in_sizes; (void)n_in; (void)out_size;
    const void* x   = d_in[0];
    const void* Wii = d_in[1];  const void* Whi = d_in[2];
    const void* Wif = d_in[3];  const void* Whf = d_in[4];
    const void* Wig = d_in[5];  const void* Whg = d_in[6];
    const void* Wio = d_in[7];  const void* Who = d_in[8];
    const void* bii = d_in[9];  const void* bhi = d_in[10];
    const void* bif = d_in[11]; const void* bhf = d_in[12];
    const void* big = d_in[13]; const void* bhg = d_in[14];
    const void* bio = d_in[15]; const void* bho = d_in[16];

    int* flags = (int*)d_ws;                        // 512 per-h-wave flags (2 KB)
    u16* hring = (u16*)((char*)d_ws + 4096);

    const size_t ring_bytes = (size_t)T_STEPS * HBUF_E * 2;          // 64 MiB
    const size_t xb_bytes   = (size_t)BATCH * T_STEPS * HD * 2;      // 64 MiB
    int ring_on = 0;
    u16* xb = nullptr;
    if (ws_size >= 4096 + ring_bytes + xb_bytes) {
        ring_on = 1;
        xb = (u16*)((char*)d_ws + 4096 + ring_bytes);
    } else if (ws_size >= 4096 + ring_bytes) {
        ring_on = 1;                                 // ring, fp32-x direct
    } else if (ws_size >= 4096 + (size_t)2 * HBUF_E * 2 + xb_bytes) {
        xb = (u16*)((char*)d_ws + 4096 + (size_t)2 * HBUF_E * 2);    // legacy 2-buf
    }

    hipMemsetAsync(d_ws, 0, 4096, stream);
    if (xb)
        hipLaunchKernelGGL(cvt_x_kernel, dim3(2048), dim3(256), 0, stream,
                           x, xb, (BATCH * T_STEPS * HD) / 4);

    hipFuncSetAttribute((const void*)lstm_persistent,
                        hipFuncAttributeMaxDynamicSharedMemorySize, SMEM_BYTES);
    hipLaunchKernelGGL(lstm_persistent, dim3(NBLK), dim3(NTHR), SMEM_BYTES, stream,
                       x, Wif, Wii, Wig, Wio, Whf, Whi, Whg, Who,
                       bif, bii, big, bio, bhf, bhi, bhg, bho,
                       hring, ring_on, xb, flags, d_out);
}